// Round 5
// baseline (242.804 us; speedup 1.0000x reference)
//
#include <hip/hip_runtime.h>
#include <hip/hip_bf16.h>

// Problem config
#define B_     4
#define S_     1024
#define H_     16
#define KVH_   4
#define D_     64
#define N_     (B_*S_)        // 4096
#define SLOTS_ 8192
#define KVD_   (KVH_*D_)      // 256
#define HD_    (H_*D_)        // 1024
#define SCL    (0.125f * 1.44269504f)   // softmax scale * log2(e), folded into Q

typedef __attribute__((ext_vector_type(8))) short bf16x8;
typedef __attribute__((ext_vector_type(4))) short bf16x4;
typedef __attribute__((ext_vector_type(4))) float f32x4;

__device__ __forceinline__ short4 f4tob4(float4 f){
    union { __hip_bfloat162 h[2]; short4 s; } u;
    u.h[0] = __float22bfloat162_rn(make_float2(f.x, f.y));
    u.h[1] = __float22bfloat162_rn(make_float2(f.z, f.w));
    return u.s;
}

// ---------------------------------------------------------------------------
// 1) copy caches (kcin -> kc, vcin -> vc); prep overwrites scattered rows after
// ---------------------------------------------------------------------------
__global__ __launch_bounds__(256) void copy_caches(
    const float4* __restrict__ kcin, const float4* __restrict__ vcin,
    float4* __restrict__ kc, float4* __restrict__ vc){
    int i = blockIdx.x*256 + threadIdx.x;      // SLOTS_*64
    kc[i] = kcin[i];
    vc[i] = vcin[i];
}

// ---------------------------------------------------------------------------
// 2) prep: read k/v once; scatter fp32 rows into caches; emit bf16 operand
//    arrays for attention: Kb[g][pos][64] row-major, Vt[g][d][S] transposed.
//    Block = (g, 64-token chunk), 256 threads.
// ---------------------------------------------------------------------------
__global__ __launch_bounds__(256) void prep_kernel(
    const float* __restrict__ k, const float* __restrict__ v,
    const int* __restrict__ slot_map,
    float* __restrict__ kc, float* __restrict__ vc,
    short* __restrict__ Kb, short* __restrict__ Vtb)
{
    __shared__ short sv[64*68];                // bf16 v-slice, pad 68 (2-way reads)
    const int tid = threadIdx.x;
    const int g   = blockIdx.x >> 4;           // 0..15 = b*4 + kvh
    const int s0  = (blockIdx.x & 15) * 64;
    const int b   = g >> 2, kvh = g & 3;

    const int sl = tid >> 2;                   // token-local 0..63
    const int cq = (tid & 3) * 16;             // dim chunk 0..48

    const int n   = b*S_ + s0 + sl;
    const int pos = s0 + sl;
    const float4* kp = (const float4*)(k + (size_t)n*KVD_ + kvh*D_ + cq);
    const float4* vp = (const float4*)(v + (size_t)n*KVD_ + kvh*D_ + cq);
    const int s = slot_map[n];

    float4 kk[4], vv[4];
    #pragma unroll
    for (int j = 0; j < 4; ++j){ kk[j] = kp[j]; vv[j] = vp[j]; }

    if (s >= 0){
        float4* kcp = (float4*)(kc + (size_t)s*KVD_ + kvh*D_ + cq);
        float4* vcp = (float4*)(vc + (size_t)s*KVD_ + kvh*D_ + cq);
        #pragma unroll
        for (int j = 0; j < 4; ++j){ kcp[j] = kk[j]; vcp[j] = vv[j]; }
    }

    short* kbp = Kb + ((size_t)g*S_ + pos)*64 + cq;
    #pragma unroll
    for (int j = 0; j < 4; ++j)
        *(short4*)(kbp + j*4) = f4tob4(kk[j]);

    #pragma unroll
    for (int j = 0; j < 4; ++j)
        *(short4*)(&sv[sl*68 + cq + j*4]) = f4tob4(vv[j]);
    __syncthreads();

    // transposed readout: thread owns dim d, 16 consecutive positions
    const int d  = tid >> 2;                   // 0..63
    const int sg = (tid & 3) * 16;             // 0..48
    union { short s[16]; bf16x8 v8[2]; } out;
    #pragma unroll
    for (int i = 0; i < 16; ++i)
        out.s[i] = sv[(sg + i)*68 + d];
    short* vtp = Vtb + ((size_t)g*64 + d)*S_ + s0 + sg;
    *(bf16x8*)(vtp)     = out.v8[0];
    *(bf16x8*)(vtp + 8) = out.v8[1];
}

// ---------------------------------------------------------------------------
// 3) attention: causal, GQA, static-max softmax, NO LDS in K-loop.
//    Block = (b, h, qt): 4 waves split the key tiles t = w, w+4, ... and
//    combine (pure sums) through one 16 KB LDS reduction at the end.
//    A-frags (K) and B-frags (Vt) are direct 16B/8B global loads from the
//    prep arrays; P never leaves registers (S^T formulation).
// ---------------------------------------------------------------------------
__global__ __launch_bounds__(256, 4) void attn_kernel(
    const float* __restrict__ q, const short* __restrict__ Kb,
    const short* __restrict__ Vtb, float* __restrict__ o)
{
    __shared__ float osum[4][16][68];          // pad 68: 2-way (free) stores
    __shared__ float lsh[4][16];

    const int tid  = threadIdx.x;
    const int w    = tid >> 6;
    const int lane = tid & 63;
    const int quad = lane >> 4;
    const int l16  = lane & 15;

    const int bid = blockIdx.x;
    const int qt  = bid & 63;
    const int bh  = bid >> 6;                  // 0..63
    const int h   = bh & 15, b = bh >> 4;
    const int kvh = h >> 2,  g = b*4 + kvh;
    const int q0  = qt * 16;
    const int ntiles = (qt >> 2) + 1;

    // ---- Q fragments (per-lane layout: q-row = l16, dim = ks*32 + quad*8 + j)
    bf16x8 qf[2];
    {
        const float* qp = q + ((size_t)(b*S_ + q0 + l16))*HD_ + h*D_ + quad*8;
        #pragma unroll
        for (int ks = 0; ks < 2; ++ks){
            float4 a0 = *(const float4*)(qp + ks*32);
            float4 a1 = *(const float4*)(qp + ks*32 + 4);
            a0.x*=SCL; a0.y*=SCL; a0.z*=SCL; a0.w*=SCL;
            a1.x*=SCL; a1.y*=SCL; a1.z*=SCL; a1.w*=SCL;
            union { short4 s[2]; bf16x8 v8; } u;
            u.s[0] = f4tob4(a0); u.s[1] = f4tob4(a1);
            qf[ks] = u.v8;
        }
    }

    f32x4 of[4];
    #pragma unroll
    for (int f2 = 0; f2 < 4; ++f2) of[f2] = (f32x4){0.f,0.f,0.f,0.f};
    float lsum = 0.f;                          // for q = q0 + l16

    const short* Kg = Kb  + (size_t)g*S_*64;
    const short* Vg = Vtb + (size_t)g*64*S_;
    const int qrow = q0 + l16;

    for (int t = w; t < ntiles; t += 4){
        const short* Kt = Kg + (size_t)t*64*64;

        // ---- A-frags for S^T = K Q^T : direct dwordx4 loads
        bf16x8 kf[2][4];
        #pragma unroll
        for (int ks = 0; ks < 2; ++ks)
            #pragma unroll
            for (int f = 0; f < 4; ++f)
                kf[ks][f] = *(const bf16x8*)(Kt + (f*16 + l16)*64 + ks*32 + quad*8);

        f32x4 sc[4];
        #pragma unroll
        for (int f = 0; f < 4; ++f) sc[f] = (f32x4){0.f,0.f,0.f,0.f};
        #pragma unroll
        for (int ks = 0; ks < 2; ++ks)
            #pragma unroll
            for (int f = 0; f < 4; ++f)
                sc[f] = __builtin_amdgcn_mfma_f32_16x16x32_bf16(kf[ks][f], qf[ks], sc[f], 0, 0, 0);

        // ---- P = exp2(S), lane holds S[q=l16][key = t*64 + f*16 + quad*4 + r]
        const bool diag = (t == ntiles - 1);
        bf16x4 pfrag[4];
        #pragma unroll
        for (int f = 0; f < 4; ++f){
            float4 pf;
            #pragma unroll
            for (int r = 0; r < 4; ++r){
                float p = __builtin_amdgcn_exp2f(sc[f][r]);
                if (diag && (t*64 + f*16 + quad*4 + r > qrow)) p = 0.f;
                lsum += p;
                ((float*)&pf)[r] = p;
            }
            union { short4 s; bf16x4 bv; } u; u.s = f4tob4(pf);
            pfrag[f] = u.bv;
        }

        // ---- O += P V : B-frags direct dwordx2 loads from transposed Vt
        #pragma unroll
        for (int f = 0; f < 4; ++f){
            #pragma unroll
            for (int f2 = 0; f2 < 4; ++f2){
                bf16x4 vf = *(const bf16x4*)(Vg + (size_t)(f2*16 + l16)*S_ + t*64 + f*16 + quad*4);
                of[f2] = __builtin_amdgcn_mfma_f32_16x16x16bf16_1k(pfrag[f], vf, of[f2], 0, 0, 0);
            }
        }
    }

    // ---- reduce lsum across quads (each lane: total for q = q0 + l16)
    lsum += __shfl_xor(lsum, 16);
    lsum += __shfl_xor(lsum, 32);

    // ---- cross-wave combine via LDS (pure sums; static max)
    #pragma unroll
    for (int f2 = 0; f2 < 4; ++f2)
        #pragma unroll
        for (int r = 0; r < 4; ++r)
            osum[w][quad*4 + r][f2*16 + l16] = of[f2][r];
    if (quad == 0) lsh[w][l16] = lsum;
    __syncthreads();

    const int row = tid >> 4;                  // 0..15
    const int dd  = (tid & 15) * 4;            // 0..60
    float4 a = make_float4(0.f,0.f,0.f,0.f);
    float lacc = 0.f;
    #pragma unroll
    for (int ww = 0; ww < 4; ++ww){
        float4 s4 = *(const float4*)(&osum[ww][row][dd]);
        a.x += s4.x; a.y += s4.y; a.z += s4.z; a.w += s4.w;
        lacc += lsh[ww][row];
    }
    const float linv = 1.f / lacc;
    float4* dst = (float4*)(o + ((size_t)(b*S_ + q0 + row))*HD_ + h*D_ + dd);
    *dst = make_float4(a.x*linv, a.y*linv, a.z*linv, a.w*linv);
}

// ---------------------------------------------------------------------------
extern "C" void kernel_launch(void* const* d_in, const int* in_sizes, int n_in,
                              void* d_out, int out_size, void* d_ws, size_t ws_size,
                              hipStream_t stream){
    (void)in_sizes; (void)n_in; (void)out_size; (void)ws_size;
    const float* q     = (const float*)d_in[0];
    const float* k     = (const float*)d_in[1];
    const float* v     = (const float*)d_in[2];
    const float* kc_in = (const float*)d_in[3];
    const float* vc_in = (const float*)d_in[4];
    const int*   slot  = (const int*)d_in[5];

    float* o  = (float*)d_out;
    float* kc = o + (size_t)N_*HD_;
    float* vc = kc + (size_t)SLOTS_*KVD_;

    short* Kb = (short*)d_ws;                              // 16*1024*64 bf16 = 2 MB
    short* Vt = Kb + (size_t)16*S_*64;                     // 2 MB

    // caches: full copy, then scatter-overwrite inside prep (stream-ordered)
    copy_caches<<<(SLOTS_*64)/256, 256, 0, stream>>>(
        (const float4*)kc_in, (const float4*)vc_in, (float4*)kc, (float4*)vc);

    prep_kernel<<<256, 256, 0, stream>>>(k, v, slot, kc, vc, Kb, Vt);

    attn_kernel<<<4096, 256, 0, stream>>>(q, Kb, Vt, o);
}

// Round 6
// 116.711 us; speedup vs baseline: 2.0804x; 2.0804x over previous
//
#include <hip/hip_runtime.h>
#include <hip/hip_bf16.h>

// Problem config
#define B_     4
#define S_     1024
#define H_     16
#define KVH_   4
#define D_     64
#define N_     (B_*S_)        // 4096
#define SLOTS_ 8192
#define KVD_   (KVH_*D_)      // 256
#define HD_    (H_*D_)        // 1024
#define SCL    (0.125f * 1.44269504f)   // softmax scale * log2(e), folded into Q

typedef __attribute__((ext_vector_type(8))) short bf16x8;
typedef __attribute__((ext_vector_type(4))) short bf16x4;
typedef __attribute__((ext_vector_type(4))) float f32x4;

__device__ __forceinline__ short4 f4tob4(float4 f){
    union { __hip_bfloat162 h[2]; short4 s; } u;
    u.h[0] = __float22bfloat162_rn(make_float2(f.x, f.y));
    u.h[1] = __float22bfloat162_rn(make_float2(f.z, f.w));
    return u.s;
}
// XOR swizzle on a 64-col short tile: 8-element groups stay contiguous,
// transposed/strided accesses spread across banks (<=2-way, free).
__device__ __forceinline__ int swz(int row, int col){
    return row*64 + (col ^ ((row & 7) << 3));
}

// ---------------------------------------------------------------------------
// 1) copy caches (kcin -> kc, vcin -> vc); prep overwrites scattered rows after
// ---------------------------------------------------------------------------
__global__ __launch_bounds__(256) void copy_caches(
    const float4* __restrict__ kcin, const float4* __restrict__ vcin,
    float4* __restrict__ kc, float4* __restrict__ vc){
    int i = blockIdx.x*256 + threadIdx.x;      // SLOTS_*64
    kc[i] = kcin[i];
    vc[i] = vcin[i];
}

// ---------------------------------------------------------------------------
// 2) prep: read k/v once; scatter fp32 rows into caches; emit bf16 operand
//    arrays: Kb[g][pos][64] row-major, Vt[g][d][S] transposed. (verified R5)
// ---------------------------------------------------------------------------
__global__ __launch_bounds__(256) void prep_kernel(
    const float* __restrict__ k, const float* __restrict__ v,
    const int* __restrict__ slot_map,
    float* __restrict__ kc, float* __restrict__ vc,
    short* __restrict__ Kb, short* __restrict__ Vtb)
{
    __shared__ short sv[64*68];                // bf16 v-slice, pad 68
    const int tid = threadIdx.x;
    const int g   = blockIdx.x >> 4;           // 0..15 = b*4 + kvh
    const int s0  = (blockIdx.x & 15) * 64;
    const int b   = g >> 2, kvh = g & 3;

    const int sl = tid >> 2;                   // token-local 0..63
    const int cq = (tid & 3) * 16;             // dim chunk 0..48

    const int n   = b*S_ + s0 + sl;
    const int pos = s0 + sl;
    const float4* kp = (const float4*)(k + (size_t)n*KVD_ + kvh*D_ + cq);
    const float4* vp = (const float4*)(v + (size_t)n*KVD_ + kvh*D_ + cq);
    const int s = slot_map[n];

    float4 kk[4], vv[4];
    #pragma unroll
    for (int j = 0; j < 4; ++j){ kk[j] = kp[j]; vv[j] = vp[j]; }

    if (s >= 0){
        float4* kcp = (float4*)(kc + (size_t)s*KVD_ + kvh*D_ + cq);
        float4* vcp = (float4*)(vc + (size_t)s*KVD_ + kvh*D_ + cq);
        #pragma unroll
        for (int j = 0; j < 4; ++j){ kcp[j] = kk[j]; vcp[j] = vv[j]; }
    }

    short* kbp = Kb + ((size_t)g*S_ + pos)*64 + cq;
    #pragma unroll
    for (int j = 0; j < 4; ++j)
        *(short4*)(kbp + j*4) = f4tob4(kk[j]);

    #pragma unroll
    for (int j = 0; j < 4; ++j)
        *(short4*)(&sv[sl*68 + cq + j*4]) = f4tob4(vv[j]);
    __syncthreads();

    const int d  = tid >> 2;                   // 0..63
    const int sg = (tid & 3) * 16;             // 0..48
    union { short s[16]; bf16x8 v8[2]; } out;
    #pragma unroll
    for (int i = 0; i < 16; ++i)
        out.s[i] = sv[(sg + i)*68 + d];
    short* vtp = Vtb + ((size_t)g*64 + d)*S_ + s0 + sg;
    *(bf16x8*)(vtp)     = out.v8[0];
    *(bf16x8*)(vtp + 8) = out.v8[1];
}

// ---------------------------------------------------------------------------
// 3) attention: causal, GQA, static-max softmax.
//    Block = (g, pair p): q-tiles p and 63-p share staged key tiles (every
//    pair = exactly 17 tile-bodies => perfect balance). Wave = one of the 4
//    query heads of kv-group g. bf16 LDS staging (reg double-buffered, one
//    barrier/tile); K-frags and V-frags read once per tile, used by both
//    q-tiles; P stays in registers (S^T + mfma_16x16x16bf16_1k).
// ---------------------------------------------------------------------------
__global__ __launch_bounds__(256, 2) void attn_kernel(
    const float* __restrict__ q, const short* __restrict__ Kb,
    const short* __restrict__ Vtb, float* __restrict__ o)
{
    __shared__ __align__(16) short sK[2][64*64];   // [buf][key][dim]
    __shared__ __align__(16) short sV[2][64*64];   // [buf][dim][key]

    const int tid  = threadIdx.x;
    const int wave = tid >> 6;
    const int lane = tid & 63;
    const int quad = lane >> 4;
    const int l16  = lane & 15;

    const int bid = blockIdx.x;                // 512 blocks
    const int g   = bid & 15;                  // low bits -> XCD L2 locality
    const int p   = bid >> 4;                  // 0..31
    const int qtA = p, qtB = 63 - p;
    const int ntA = (qtA >> 2) + 1;            // tiles for A (subset of B's)
    const int ntB = (qtB >> 2) + 1;

    const int b = g >> 2, kvh = g & 3;
    const int h = kvh*4 + wave;

    // ---- Q fragments for both q-tiles (per-lane: row=l16, k=ks*32+quad*8+j)
    bf16x8 qfA[2], qfB[2];
    {
        const float* qpA = q + ((size_t)(b*S_ + qtA*16 + l16))*HD_ + h*D_ + quad*8;
        const float* qpB = q + ((size_t)(b*S_ + qtB*16 + l16))*HD_ + h*D_ + quad*8;
        #pragma unroll
        for (int ks = 0; ks < 2; ++ks){
            float4 a0 = *(const float4*)(qpA + ks*32);
            float4 a1 = *(const float4*)(qpA + ks*32 + 4);
            float4 b0 = *(const float4*)(qpB + ks*32);
            float4 b1 = *(const float4*)(qpB + ks*32 + 4);
            a0.x*=SCL; a0.y*=SCL; a0.z*=SCL; a0.w*=SCL;
            a1.x*=SCL; a1.y*=SCL; a1.z*=SCL; a1.w*=SCL;
            b0.x*=SCL; b0.y*=SCL; b0.z*=SCL; b0.w*=SCL;
            b1.x*=SCL; b1.y*=SCL; b1.z*=SCL; b1.w*=SCL;
            union { short4 s[2]; bf16x8 v8; } ua, ub;
            ua.s[0] = f4tob4(a0); ua.s[1] = f4tob4(a1);
            ub.s[0] = f4tob4(b0); ub.s[1] = f4tob4(b1);
            qfA[ks] = ua.v8; qfB[ks] = ub.v8;
        }
    }

    f32x4 ofA[4], ofB[4];
    #pragma unroll
    for (int f2 = 0; f2 < 4; ++f2){
        ofA[f2] = (f32x4){0.f,0.f,0.f,0.f};
        ofB[f2] = (f32x4){0.f,0.f,0.f,0.f};
    }
    float lsA = 0.f, lsB = 0.f;
    const int qrowA = qtA*16 + l16, qrowB = qtB*16 + l16;

    const short* Kg = Kb  + (size_t)g*S_*64;
    const short* Vg = Vtb + (size_t)g*64*S_;

    // ---- staging: thread owns key-row rs (K) / dim-row rs (V), 16-col chunk
    const int rs = tid >> 2;                   // 0..63
    const int cg = (tid & 3) * 16;             // 0,16,32,48

    bf16x8 kst[2], vst[2];
    kst[0] = *(const bf16x8*)(Kg + (size_t)rs*64 + cg);
    kst[1] = *(const bf16x8*)(Kg + (size_t)rs*64 + cg + 8);
    vst[0] = *(const bf16x8*)(Vg + (size_t)rs*S_ + cg);
    vst[1] = *(const bf16x8*)(Vg + (size_t)rs*S_ + cg + 8);

    // softmax + PV for one q-tile (P in registers; pure-sum online state)
    auto pv_body = [&](const f32x4* sc, f32x4* of, float& lsum,
                       int qrow, bool diag, int t, const short* V_){
        bf16x4 pfrag[4];
        #pragma unroll
        for (int f = 0; f < 4; ++f){
            float4 pf;
            #pragma unroll
            for (int r = 0; r < 4; ++r){
                float pe = __builtin_amdgcn_exp2f(sc[f][r]);
                if (diag && (t*64 + f*16 + quad*4 + r > qrow)) pe = 0.f;
                lsum += pe;
                ((float*)&pf)[r] = pe;
            }
            union { short4 s; bf16x4 bv; } u; u.s = f4tob4(pf);
            pfrag[f] = u.bv;
        }
        #pragma unroll
        for (int f = 0; f < 4; ++f){
            #pragma unroll
            for (int f2 = 0; f2 < 4; ++f2){
                bf16x4 vf = *(const bf16x4*)(&V_[swz(f2*16 + l16, f*16 + quad*4)]);
                of[f2] = __builtin_amdgcn_mfma_f32_16x16x16bf16_1k(pfrag[f], vf, of[f2], 0, 0, 0);
            }
        }
    };

    for (int t = 0; t < ntB; ++t){
        short* K_ = (short*)sK[t & 1];
        short* V_ = (short*)sV[t & 1];
        // write staged regs (straight copies; Vt already transposed in prep)
        *(bf16x8*)(&K_[swz(rs, cg)])     = kst[0];
        *(bf16x8*)(&K_[swz(rs, cg + 8)]) = kst[1];
        *(bf16x8*)(&V_[swz(rs, cg)])     = vst[0];
        *(bf16x8*)(&V_[swz(rs, cg + 8)]) = vst[1];
        // prefetch next tile (vmcnt-wait lands at next iteration's LDS write)
        if (t + 1 < ntB){
            kst[0] = *(const bf16x8*)(Kg + (size_t)((t+1)*64 + rs)*64 + cg);
            kst[1] = *(const bf16x8*)(Kg + (size_t)((t+1)*64 + rs)*64 + cg + 8);
            vst[0] = *(const bf16x8*)(Vg + (size_t)rs*S_ + (t+1)*64 + cg);
            vst[1] = *(const bf16x8*)(Vg + (size_t)rs*S_ + (t+1)*64 + cg + 8);
        }
        __syncthreads();   // buf[t&1] staged; buf[(t+1)&1] still being read? no:
                           // reads of t-1 finished before this wave's t-1 compute
                           // ended, and writes here target buf[t&1] (t-2's buffer,
                           // protected by the t-1 barrier all waves passed).

        // ---- K-frags: read once, shared by both q-tiles (same K for GQA pair)
        bf16x8 kf[2][4];
        #pragma unroll
        for (int ks = 0; ks < 2; ++ks)
            #pragma unroll
            for (int f = 0; f < 4; ++f)
                kf[ks][f] = *(const bf16x8*)(&K_[swz(f*16 + l16, ks*32 + quad*8)]);

        const bool actA = (t < ntA);

        // ---- S^T = K Q^T for both q-tiles
        f32x4 scB[4];
        #pragma unroll
        for (int f = 0; f < 4; ++f) scB[f] = (f32x4){0.f,0.f,0.f,0.f};
        #pragma unroll
        for (int ks = 0; ks < 2; ++ks)
            #pragma unroll
            for (int f = 0; f < 4; ++f)
                scB[f] = __builtin_amdgcn_mfma_f32_16x16x32_bf16(kf[ks][f], qfB[ks], scB[f], 0, 0, 0);
        pv_body(scB, ofB, lsB, qrowB, t == ntB - 1, t, V_);

        if (actA){
            f32x4 scA[4];
            #pragma unroll
            for (int f = 0; f < 4; ++f) scA[f] = (f32x4){0.f,0.f,0.f,0.f};
            #pragma unroll
            for (int ks = 0; ks < 2; ++ks)
                #pragma unroll
                for (int f = 0; f < 4; ++f)
                    scA[f] = __builtin_amdgcn_mfma_f32_16x16x32_bf16(kf[ks][f], qfA[ks], scA[f], 0, 0, 0);
            pv_body(scA, ofA, lsA, qrowA, t == ntA - 1, t, V_);
        }
    }

    // ---- finalize both q-tiles
    auto epilogue = [&](f32x4* of, float lsum, int qt){
        lsum += __shfl_xor(lsum, 16);
        lsum += __shfl_xor(lsum, 32);          // all lanes: total for q = qt*16+l16
        float linv[4];
        #pragma unroll
        for (int r = 0; r < 4; ++r)
            linv[r] = 1.f / __shfl(lsum, quad*4 + r);
        #pragma unroll
        for (int f2 = 0; f2 < 4; ++f2){
            #pragma unroll
            for (int r = 0; r < 4; ++r){
                const int row = qt*16 + quad*4 + r;
                o[((size_t)(b*S_ + row))*HD_ + h*D_ + f2*16 + l16] = of[f2][r] * linv[r];
            }
        }
    };
    epilogue(ofA, lsA, qtA);
    epilogue(ofB, lsB, qtB);
}

// ---------------------------------------------------------------------------
extern "C" void kernel_launch(void* const* d_in, const int* in_sizes, int n_in,
                              void* d_out, int out_size, void* d_ws, size_t ws_size,
                              hipStream_t stream){
    (void)in_sizes; (void)n_in; (void)out_size; (void)ws_size;
    const float* q     = (const float*)d_in[0];
    const float* k     = (const float*)d_in[1];
    const float* v     = (const float*)d_in[2];
    const float* kc_in = (const float*)d_in[3];
    const float* vc_in = (const float*)d_in[4];
    const int*   slot  = (const int*)d_in[5];

    float* o  = (float*)d_out;
    float* kc = o + (size_t)N_*HD_;
    float* vc = kc + (size_t)SLOTS_*KVD_;

    short* Kb = (short*)d_ws;                              // 16*1024*64 bf16 = 2 MB
    short* Vt = Kb + (size_t)16*S_*64;                     // 2 MB

    copy_caches<<<(SLOTS_*64)/256, 256, 0, stream>>>(
        (const float4*)kc_in, (const float4*)vc_in, (float4*)kc, (float4*)vc);

    prep_kernel<<<256, 256, 0, stream>>>(k, v, slot, kc, vc, Kb, Vt);

    attn_kernel<<<512, 256, 0, stream>>>(q, Kb, Vt, o);
}